// Round 1
// baseline (389.234 us; speedup 1.0000x reference)
//
#include <hip/hip_runtime.h>
#include <hip/hip_bf16.h>

typedef __attribute__((ext_vector_type(8))) __bf16 bf16x8;
typedef __attribute__((ext_vector_type(4))) float f32x4;

#define MFMA16(a,b,c) __builtin_amdgcn_mfma_f32_16x16x32_bf16(a,b,c,0,0,0)

__device__ __forceinline__ unsigned short f2b(float x){
  __hip_bfloat16 h = __float2bfloat16(x);
  return __builtin_bit_cast(unsigned short, h);
}

// ---------------- RoPE table: cos/sin for 1024 positions x 32 freqs ---------
__global__ void k_rope_table(float* __restrict__ ct, float* __restrict__ st){
  int i = blockIdx.x*256 + threadIdx.x;   // 0..32767
  int t = i >> 5, f = i & 31;
  float freq = powf(10000.0f, -(float)f/32.0f);
  float a = (float)t * freq;
  ct[i] = cosf(a);
  st[i] = sinf(a);
}

// ---------------- Fused QKV projection + RoPE -------------------------------
// X (2048 x 2048) fp32 @ [Wq|Wk|Wv] -> q (2048x2048), k (2048x512), v (2048x512) bf16
__global__ __launch_bounds__(256) void k_qkv(
    const float* __restrict__ X, const float* __restrict__ Wq,
    const float* __restrict__ Wk, const float* __restrict__ Wv,
    const float* __restrict__ ct, const float* __restrict__ st,
    unsigned short* __restrict__ qb, unsigned short* __restrict__ kb,
    unsigned short* __restrict__ vb)
{
  __shared__ unsigned short As[128][40];   // [m][k] bf16, +8 pad (2-way max)
  __shared__ unsigned short Bs[128][40];   // [n][k] bf16 (transposed), +8 pad
  const int bm = blockIdx.y * 128;
  const int bn_g = blockIdx.x * 128;       // global col in [0,3072)
  const float* W; int ncol, bn_l, wtype;
  if (bn_g < 2048)      { W=Wq; ncol=2048; bn_l=bn_g;      wtype=0; }
  else if (bn_g < 2560) { W=Wk; ncol=512;  bn_l=bn_g-2048; wtype=1; }
  else                  { W=Wv; ncol=512;  bn_l=bn_g-2560; wtype=2; }

  const int tid=threadIdx.x, wave=tid>>6, lane=tid&63;
  const int lrow=lane&15, kgrp=lane>>4;
  const int wm=(wave>>1)*64, wn=(wave&1)*64;

  f32x4 acc[4][4] = {};
  const int atr = tid>>3, atc = tid&7;     // A staging: 32 rows/pass, 8 f32x4/row
  const int bkr = tid>>5, bnc = tid&31;    // B staging: 8 k-rows/pass, 32 f32x4/row

  for (int k0=0;k0<2048;k0+=32) {
    __syncthreads();
    #pragma unroll
    for (int it=0; it<4; ++it) {
      int r = atr + 32*it;
      float4 v = *(const float4*)&X[(size_t)(bm+r)*2048 + k0 + atc*4];
      unsigned short* dst = &As[r][atc*4];
      dst[0]=f2b(v.x); dst[1]=f2b(v.y); dst[2]=f2b(v.z); dst[3]=f2b(v.w);
    }
    #pragma unroll
    for (int it=0; it<4; ++it) {
      int kk = bkr + 8*it;
      float4 v = *(const float4*)&W[(size_t)(k0+kk)*ncol + bn_l + bnc*4];
      Bs[bnc*4+0][kk]=f2b(v.x); Bs[bnc*4+1][kk]=f2b(v.y);
      Bs[bnc*4+2][kk]=f2b(v.z); Bs[bnc*4+3][kk]=f2b(v.w);
    }
    __syncthreads();
    bf16x8 a[4], b[4];
    #pragma unroll
    for (int mi=0;mi<4;mi++) a[mi] = *(const bf16x8*)&As[wm+mi*16+lrow][kgrp*8];
    #pragma unroll
    for (int ni=0;ni<4;ni++) b[ni] = *(const bf16x8*)&Bs[wn+ni*16+lrow][kgrp*8];
    #pragma unroll
    for (int mi=0;mi<4;mi++)
      #pragma unroll
      for (int ni=0;ni<4;ni++)
        acc[mi][ni] = MFMA16(a[mi], b[ni], acc[mi][ni]);
  }

  // Epilogue: C/D layout col = lane&15, row = (lane>>4)*4 + reg.
  // RoPE pair (2d,2d+1) sits in lanes (l, l^1) since col parity = lane bit0.
  #pragma unroll
  for (int mi=0;mi<4;mi++) {
    #pragma unroll
    for (int ni=0;ni<4;ni++) {
      int gr0 = bm + wm + mi*16 + kgrp*4;
      int gc  = bn_g + wn + ni*16 + lrow;
      if (wtype==2) {
        int c = gc - 2560;
        #pragma unroll
        for (int r=0;r<4;r++)
          vb[(size_t)(gr0+r)*512 + c] = f2b(acc[mi][ni][r]);
      } else {
        int d = gc & 63, fi = d >> 1, odd = d & 1;
        #pragma unroll
        for (int r=0;r<4;r++) {
          float x = acc[mi][ni][r];
          float p = __shfl_xor(x, 1, 64);
          int srow = (gr0 + r) & 1023;          // token position within sequence
          float c = ct[srow*32 + fi], sn = st[srow*32 + fi];
          float o = odd ? (x*c + p*sn) : (x*c - p*sn);
          if (wtype==0) qb[(size_t)(gr0+r)*2048 + gc] = f2b(o);
          else          kb[(size_t)(gr0+r)*512 + (gc-2048)] = f2b(o);
        }
      }
    }
  }
}

// ---------------- Flash attention (GQA, causal) -----------------------------
// grid: 512 = B(2) * H(32) * QTILES(8); block 256 = 4 waves x 32 q-rows
__global__ __launch_bounds__(256) void k_attn(
    const unsigned short* __restrict__ qb, const unsigned short* __restrict__ kb,
    const unsigned short* __restrict__ vb, unsigned short* __restrict__ ctxb)
{
  __shared__ unsigned short Qs[128][72];   // [q][d]
  __shared__ unsigned short Ks[128][72];   // [kv][d]
  __shared__ unsigned short Vt[64][136];   // [d][kv] (transposed)
  __shared__ unsigned short Ps[128][136];  // [q][kv] P tile

  const int qt = blockIdx.x & 7;
  const int h  = (blockIdx.x >> 3) & 31;
  const int b  = blockIdx.x >> 8;
  const int kvh = h >> 2;                  // G = 4

  const int tid=threadIdx.x, wave=tid>>6, lane=tid&63;
  const int lrow=lane&15, kgrp=lane>>4;
  const int wq = wave*32;

  { // load Q tile (128 x 64 bf16)
    int r = tid>>1, half = tid&1;
    const unsigned short* src = qb + (size_t)(b*1024 + qt*128 + r)*2048 + h*64 + half*32;
    #pragma unroll
    for (int u=0;u<4;u++)
      *(uint4*)&Qs[r][half*32 + u*8] = *(const uint4*)&src[u*8];
  }
  __syncthreads();

  bf16x8 qa[2][2];
  #pragma unroll
  for (int ks=0;ks<2;ks++)
    #pragma unroll
    for (int mi=0;mi<2;mi++)
      qa[ks][mi] = *(const bf16x8*)&Qs[wq+mi*16+lrow][ks*32+kgrp*8];

  float m_run[2][4], l_run[2][4];
  f32x4 out[2][4] = {};
  #pragma unroll
  for (int mi=0;mi<2;mi++)
    #pragma unroll
    for (int r=0;r<4;r++){ m_run[mi][r] = -1e30f; l_run[mi][r]=0.f; }

  for (int j=0;j<=qt;j++) {
    __syncthreads();
    { // stage K tile + V tile (transposed)
      int r = tid>>1, half = tid&1;
      const unsigned short* ksrc = kb + (size_t)(b*1024 + j*128 + r)*512 + kvh*64 + half*32;
      #pragma unroll
      for (int u=0;u<4;u++)
        *(uint4*)&Ks[r][half*32 + u*8] = *(const uint4*)&ksrc[u*8];
      const unsigned short* vsrc = vb + (size_t)(b*1024 + j*128 + r)*512 + kvh*64 + half*32;
      #pragma unroll
      for (int u=0;u<4;u++) {
        uint4 vv = *(const uint4*)&vsrc[u*8];
        const unsigned short* pp = (const unsigned short*)&vv;
        #pragma unroll
        for (int e=0;e<8;e++) Vt[half*32+u*8+e][r] = pp[e];
      }
    }
    __syncthreads();

    // S = Q K^T  (32 q-rows x 128 kv per wave)
    f32x4 sc[2][8] = {};
    #pragma unroll
    for (int ks=0;ks<2;ks++) {
      #pragma unroll
      for (int ni=0;ni<8;ni++) {
        bf16x8 kf = *(const bf16x8*)&Ks[ni*16+lrow][ks*32+kgrp*8];
        sc[0][ni] = MFMA16(qa[ks][0], kf, sc[0][ni]);
        sc[1][ni] = MFMA16(qa[ks][1], kf, sc[1][ni]);
      }
    }

    const float scale = 0.125f;              // 1/sqrt(64)
    if (j == qt) {
      #pragma unroll
      for (int mi=0;mi<2;mi++)
        #pragma unroll
        for (int ni=0;ni<8;ni++)
          #pragma unroll
          for (int r=0;r<4;r++) {
            int qrow = wq + mi*16 + kgrp*4 + r;
            int kcol = ni*16 + lrow;
            float sv = sc[mi][ni][r]*scale;
            sc[mi][ni][r] = (kcol > qrow) ? -1e30f : sv;
          }
    } else {
      #pragma unroll
      for (int mi=0;mi<2;mi++)
        #pragma unroll
        for (int ni=0;ni<8;ni++)
          #pragma unroll
          for (int r=0;r<4;r++)
            sc[mi][ni][r] *= scale;
    }

    // online softmax (row stats shared across each 16-lane col group)
    #pragma unroll
    for (int mi=0;mi<2;mi++) {
      #pragma unroll
      for (int r=0;r<4;r++) {
        float mx = sc[mi][0][r];
        #pragma unroll
        for (int ni=1;ni<8;ni++) mx = fmaxf(mx, sc[mi][ni][r]);
        mx = fmaxf(mx, __shfl_xor(mx,1,64));
        mx = fmaxf(mx, __shfl_xor(mx,2,64));
        mx = fmaxf(mx, __shfl_xor(mx,4,64));
        mx = fmaxf(mx, __shfl_xor(mx,8,64));
        float mnew = fmaxf(m_run[mi][r], mx);
        float corr = __expf(m_run[mi][r] - mnew);
        m_run[mi][r] = mnew;
        float rsum = 0.f;
        #pragma unroll
        for (int ni=0;ni<8;ni++) {
          float p = __expf(sc[mi][ni][r] - mnew);
          sc[mi][ni][r] = p;
          rsum += p;
        }
        rsum += __shfl_xor(rsum,1,64);
        rsum += __shfl_xor(rsum,2,64);
        rsum += __shfl_xor(rsum,4,64);
        rsum += __shfl_xor(rsum,8,64);
        l_run[mi][r] = l_run[mi][r]*corr + rsum;
        #pragma unroll
        for (int di=0;di<4;di++) out[mi][di][r] *= corr;
      }
    }

    // P -> LDS (C-layout -> A-layout transpose through LDS)
    #pragma unroll
    for (int mi=0;mi<2;mi++)
      #pragma unroll
      for (int ni=0;ni<8;ni++)
        #pragma unroll
        for (int r=0;r<4;r++)
          Ps[wq + mi*16 + kgrp*4 + r][ni*16 + lrow] = f2b(sc[mi][ni][r]);
    __syncthreads();

    // O += P V
    #pragma unroll
    for (int ks2=0;ks2<4;ks2++) {
      bf16x8 pa[2];
      #pragma unroll
      for (int mi=0;mi<2;mi++) pa[mi] = *(const bf16x8*)&Ps[wq+mi*16+lrow][ks2*32+kgrp*8];
      #pragma unroll
      for (int di=0;di<4;di++) {
        bf16x8 vf = *(const bf16x8*)&Vt[di*16+lrow][ks2*32+kgrp*8];
        out[0][di] = MFMA16(pa[0], vf, out[0][di]);
        out[1][di] = MFMA16(pa[1], vf, out[1][di]);
      }
    }
  }

  #pragma unroll
  for (int mi=0;mi<2;mi++)
    #pragma unroll
    for (int di=0;di<4;di++)
      #pragma unroll
      for (int r=0;r<4;r++) {
        float o = out[mi][di][r] / l_run[mi][r];
        ctxb[(size_t)(b*1024 + qt*128 + wq + mi*16 + kgrp*4 + r)*2048
             + h*64 + di*16 + lrow] = f2b(o);
      }
}

// ---------------- Output projection: ctx (bf16) @ Wo -> out fp32 ------------
__global__ __launch_bounds__(256) void k_oproj(
    const unsigned short* __restrict__ ctxb, const float* __restrict__ Wo,
    float* __restrict__ out)
{
  __shared__ unsigned short As[128][40];
  __shared__ unsigned short Bs[128][40];
  const int bm = blockIdx.y*128, bn = blockIdx.x*128;
  const int tid=threadIdx.x, wave=tid>>6, lane=tid&63;
  const int lrow=lane&15, kgrp=lane>>4;
  const int wm=(wave>>1)*64, wn=(wave&1)*64;
  f32x4 acc[4][4] = {};
  const int atr = tid>>1, ath = tid&1;
  const int bkr = tid>>5, bnc = tid&31;

  for (int k0=0;k0<2048;k0+=32) {
    __syncthreads();
    { // A: bf16 copy, 16 ushorts per thread
      const unsigned short* src = ctxb + (size_t)(bm+atr)*2048 + k0 + ath*16;
      *(uint4*)&As[atr][ath*16]   = *(const uint4*)&src[0];
      *(uint4*)&As[atr][ath*16+8] = *(const uint4*)&src[8];
    }
    #pragma unroll
    for (int it=0; it<4; ++it) {
      int kk = bkr + 8*it;
      float4 v = *(const float4*)&Wo[(size_t)(k0+kk)*2048 + bn + bnc*4];
      Bs[bnc*4+0][kk]=f2b(v.x); Bs[bnc*4+1][kk]=f2b(v.y);
      Bs[bnc*4+2][kk]=f2b(v.z); Bs[bnc*4+3][kk]=f2b(v.w);
    }
    __syncthreads();
    bf16x8 a[4], b[4];
    #pragma unroll
    for (int mi=0;mi<4;mi++) a[mi] = *(const bf16x8*)&As[wm+mi*16+lrow][kgrp*8];
    #pragma unroll
    for (int ni=0;ni<4;ni++) b[ni] = *(const bf16x8*)&Bs[wn+ni*16+lrow][kgrp*8];
    #pragma unroll
    for (int mi=0;mi<4;mi++)
      #pragma unroll
      for (int ni=0;ni<4;ni++)
        acc[mi][ni] = MFMA16(a[mi], b[ni], acc[mi][ni]);
  }

  #pragma unroll
  for (int mi=0;mi<4;mi++)
    #pragma unroll
    for (int ni=0;ni<4;ni++) {
      int gr0 = bm + wm + mi*16 + kgrp*4;
      int gc  = bn + wn + ni*16 + lrow;
      #pragma unroll
      for (int r=0;r<4;r++)
        out[(size_t)(gr0+r)*2048 + gc] = acc[mi][ni][r];
    }
}

// ---------------- launch ----------------------------------------------------
extern "C" void kernel_launch(void* const* d_in, const int* in_sizes, int n_in,
                              void* d_out, int out_size, void* d_ws, size_t ws_size,
                              hipStream_t stream)
{
  const float* X  = (const float*)d_in[0];
  const float* Wq = (const float*)d_in[1];
  const float* Wk = (const float*)d_in[2];
  const float* Wv = (const float*)d_in[3];
  const float* Wo = (const float*)d_in[4];
  float* out = (float*)d_out;
  char* ws = (char*)d_ws;

  float* ct = (float*)ws;                                  // 128 KB
  float* st = (float*)(ws + 128*1024);                     // 128 KB
  unsigned short* qb   = (unsigned short*)(ws + 256*1024);                 // 8 MB
  unsigned short* kb   = (unsigned short*)(ws + 256*1024 + 8ull*1048576);  // 2 MB
  unsigned short* vb   = (unsigned short*)(ws + 256*1024 + 10ull*1048576); // 2 MB
  unsigned short* ctxb = (unsigned short*)(ws + 256*1024 + 12ull*1048576); // 8 MB

  hipLaunchKernelGGL(k_rope_table, dim3(128), dim3(256), 0, stream, ct, st);
  hipLaunchKernelGGL(k_qkv, dim3(24,16), dim3(256), 0, stream,
                     X, Wq, Wk, Wv, ct, st, qb, kb, vb);
  hipLaunchKernelGGL(k_attn, dim3(512), dim3(256), 0, stream, qb, kb, vb, ctxb);
  hipLaunchKernelGGL(k_oproj, dim3(16,16), dim3(256), 0, stream, ctxb, Wo, out);
}

// Round 2
// 220.476 us; speedup vs baseline: 1.7654x; 1.7654x over previous
//
#include <hip/hip_runtime.h>
#include <hip/hip_bf16.h>

typedef __attribute__((ext_vector_type(8))) __bf16 bf16x8;
typedef __attribute__((ext_vector_type(4))) float f32x4;

#define MFMA16(a,b,c) __builtin_amdgcn_mfma_f32_16x16x32_bf16(a,b,c,0,0,0)

__device__ __forceinline__ unsigned short f2b(float x){
  __hip_bfloat16 h = __float2bfloat16(x);
  return __builtin_bit_cast(unsigned short, h);
}

// async global->LDS, 16B per lane. LDS dest is wave-uniform base + lane*16.
__device__ __forceinline__ void gload16(const unsigned short* g, unsigned short* l){
  __builtin_amdgcn_global_load_lds(
      (const __attribute__((address_space(1))) unsigned int*)g,
      (__attribute__((address_space(3))) unsigned int*)l, 16, 0, 0);
}

// ---------------- RoPE table: cos/sin for 1024 positions x 32 freqs ---------
__global__ void k_rope_table(float* __restrict__ ct, float* __restrict__ st){
  int i = blockIdx.x*256 + threadIdx.x;   // 0..32767
  int t = i >> 5, f = i & 31;
  float freq = powf(10000.0f, -(float)f/32.0f);
  float a = (float)t * freq;
  ct[i] = cosf(a);
  st[i] = sinf(a);
}

// ---------------- X fp32 -> bf16 (row-major) --------------------------------
__global__ void k_cvt(const float* __restrict__ src, unsigned short* __restrict__ dst, int n4){
  int i = blockIdx.x*256 + threadIdx.x;
  int stride = gridDim.x*256;
  for (; i < n4; i += stride){
    float4 v = ((const float4*)src)[i];
    ushort4 o; o.x=f2b(v.x); o.y=f2b(v.y); o.z=f2b(v.z); o.w=f2b(v.w);
    ((ushort4*)dst)[i] = o;
  }
}

// ---------------- W [K][N] fp32 -> Wt [N][K] bf16 (fused Q|K|V) -------------
__global__ __launch_bounds__(256) void k_prep_wt(
    const float* __restrict__ Wq, const float* __restrict__ Wk,
    const float* __restrict__ Wv, unsigned short* __restrict__ Wt){
  __shared__ float t[32][33];
  int n0 = blockIdx.x*32, k0 = blockIdx.y*32;
  const float* src; int N, nl;
  if (n0 < 2048)      { src=Wq; N=2048; nl=n0; }
  else if (n0 < 2560) { src=Wk; N=512;  nl=n0-2048; }
  else                { src=Wv; N=512;  nl=n0-2560; }
  int r = threadIdx.x>>5, c = threadIdx.x&31;
  #pragma unroll
  for (int it=0; it<4; ++it)
    t[r+8*it][c] = src[(size_t)(k0+r+8*it)*N + nl + c];
  __syncthreads();
  #pragma unroll
  for (int it=0; it<4; ++it)
    Wt[(size_t)(n0+r+8*it)*2048 + k0 + c] = f2b(t[c][r+8*it]);
}

__global__ __launch_bounds__(256) void k_prep_wo(
    const float* __restrict__ Wo, unsigned short* __restrict__ Wot){
  __shared__ float t[32][33];
  int n0 = blockIdx.x*32, k0 = blockIdx.y*32;
  int r = threadIdx.x>>5, c = threadIdx.x&31;
  #pragma unroll
  for (int it=0; it<4; ++it)
    t[r+8*it][c] = Wo[(size_t)(k0+r+8*it)*2048 + n0 + c];
  __syncthreads();
  #pragma unroll
  for (int it=0; it<4; ++it)
    Wot[(size_t)(n0+r+8*it)*2048 + k0 + c] = f2b(t[c][r+8*it]);
}

// ---------------- QKV GEMM (m97 structure) + RoPE epilogue ------------------
__global__ __launch_bounds__(256) void k_qkv(
    const unsigned short* __restrict__ A, const unsigned short* __restrict__ Bt,
    const float* __restrict__ ct, const float* __restrict__ st,
    unsigned short* __restrict__ qb, unsigned short* __restrict__ kb,
    unsigned short* __restrict__ vb)
{
  __shared__ unsigned short As[128*32];
  __shared__ unsigned short Bs[128*32];
  const int bm = blockIdx.y*128, bn_g = blockIdx.x*128;
  const int tid=threadIdx.x, wave=tid>>6, lane=tid&63;
  const int lrow=lane&15, kgrp=lane>>4;
  const int wm=(wave>>1)*64, wn=(wave&1)*64;
  f32x4 acc[4][4] = {};

  for (int k0=0;k0<2048;k0+=32){
    __syncthreads();
    #pragma unroll
    for (int it=0; it<2; ++it){
      int idx = it*256 + tid;
      int row = idx>>2, c16 = idx&3;
      gload16(&A [(size_t)(bm  +row)*2048 + k0 + c16*8], &As[(it*256 + wave*64)*8]);
      gload16(&Bt[(size_t)(bn_g+row)*2048 + k0 + c16*8], &Bs[(it*256 + wave*64)*8]);
    }
    __syncthreads();
    bf16x8 a[4], b[4];
    #pragma unroll
    for (int mi=0;mi<4;mi++) a[mi] = *(const bf16x8*)&As[(wm+mi*16+lrow)*32 + kgrp*8];
    #pragma unroll
    for (int ni=0;ni<4;ni++) b[ni] = *(const bf16x8*)&Bs[(wn+ni*16+lrow)*32 + kgrp*8];
    #pragma unroll
    for (int mi=0;mi<4;mi++)
      #pragma unroll
      for (int ni=0;ni<4;ni++)
        acc[mi][ni] = MFMA16(a[mi], b[ni], acc[mi][ni]);
  }

  const int wtype = (bn_g < 2048) ? 0 : (bn_g < 2560 ? 1 : 2);
  #pragma unroll
  for (int mi=0;mi<4;mi++){
    #pragma unroll
    for (int ni=0;ni<4;ni++){
      int gr0 = bm + wm + mi*16 + kgrp*4;
      int gc  = bn_g + wn + ni*16 + lrow;
      if (wtype==2){
        int c = gc - 2560;
        #pragma unroll
        for (int r=0;r<4;r++)
          vb[(size_t)(gr0+r)*512 + c] = f2b(acc[mi][ni][r]);
      } else {
        int d = gc & 63, fi = d >> 1, odd = d & 1;
        #pragma unroll
        for (int r=0;r<4;r++){
          float x = acc[mi][ni][r];
          float p = __shfl_xor(x, 1, 64);
          int srow = (gr0 + r) & 1023;
          float c = ct[srow*32 + fi], sn = st[srow*32 + fi];
          float o = odd ? (x*c + p*sn) : (x*c - p*sn);
          if (wtype==0) qb[(size_t)(gr0+r)*2048 + gc] = f2b(o);
          else          kb[(size_t)(gr0+r)*512 + (gc-2048)] = f2b(o);
        }
      }
    }
  }
}

// ---------------- Flash attention (GQA, causal) -----------------------------
__global__ __launch_bounds__(256) void k_attn(
    const unsigned short* __restrict__ qb, const unsigned short* __restrict__ kb,
    const unsigned short* __restrict__ vb, unsigned short* __restrict__ ctxb)
{
  __shared__ unsigned short Qs[128][72];
  __shared__ unsigned short Ks[128][72];
  __shared__ unsigned short Vt[64][136];
  __shared__ unsigned short Ps[128][136];

  const int qt = blockIdx.x & 7;
  const int h  = (blockIdx.x >> 3) & 31;
  const int b  = blockIdx.x >> 8;
  const int kvh = h >> 2;

  const int tid=threadIdx.x, wave=tid>>6, lane=tid&63;
  const int lrow=lane&15, kgrp=lane>>4;
  const int wq = wave*32;

  {
    int r = tid>>1, half = tid&1;
    const unsigned short* src = qb + (size_t)(b*1024 + qt*128 + r)*2048 + h*64 + half*32;
    #pragma unroll
    for (int u=0;u<4;u++)
      *(uint4*)&Qs[r][half*32 + u*8] = *(const uint4*)&src[u*8];
  }
  __syncthreads();

  bf16x8 qa[2][2];
  #pragma unroll
  for (int ks=0;ks<2;ks++)
    #pragma unroll
    for (int mi=0;mi<2;mi++)
      qa[ks][mi] = *(const bf16x8*)&Qs[wq+mi*16+lrow][ks*32+kgrp*8];

  float m_run[2][4], l_run[2][4];
  f32x4 out[2][4] = {};
  #pragma unroll
  for (int mi=0;mi<2;mi++)
    #pragma unroll
    for (int r=0;r<4;r++){ m_run[mi][r] = -1e30f; l_run[mi][r]=0.f; }

  for (int j=0;j<=qt;j++){
    __syncthreads();
    {
      int r = tid>>1, half = tid&1;
      const unsigned short* ksrc = kb + (size_t)(b*1024 + j*128 + r)*512 + kvh*64 + half*32;
      #pragma unroll
      for (int u=0;u<4;u++)
        *(uint4*)&Ks[r][half*32 + u*8] = *(const uint4*)&ksrc[u*8];
      const unsigned short* vsrc = vb + (size_t)(b*1024 + j*128 + r)*512 + kvh*64 + half*32;
      #pragma unroll
      for (int u=0;u<4;u++){
        uint4 vv = *(const uint4*)&vsrc[u*8];
        const unsigned short* pp = (const unsigned short*)&vv;
        #pragma unroll
        for (int e=0;e<8;e++) Vt[half*32+u*8+e][r] = pp[e];
      }
    }
    __syncthreads();

    f32x4 sc[2][8] = {};
    #pragma unroll
    for (int ks=0;ks<2;ks++){
      #pragma unroll
      for (int ni=0;ni<8;ni++){
        bf16x8 kf = *(const bf16x8*)&Ks[ni*16+lrow][ks*32+kgrp*8];
        sc[0][ni] = MFMA16(qa[ks][0], kf, sc[0][ni]);
        sc[1][ni] = MFMA16(qa[ks][1], kf, sc[1][ni]);
      }
    }

    const float scale = 0.125f;
    if (j == qt){
      #pragma unroll
      for (int mi=0;mi<2;mi++)
        #pragma unroll
        for (int ni=0;ni<8;ni++)
          #pragma unroll
          for (int r=0;r<4;r++){
            int qrow = wq + mi*16 + kgrp*4 + r;
            int kcol = ni*16 + lrow;
            float sv = sc[mi][ni][r]*scale;
            sc[mi][ni][r] = (kcol > qrow) ? -1e30f : sv;
          }
    } else {
      #pragma unroll
      for (int mi=0;mi<2;mi++)
        #pragma unroll
        for (int ni=0;ni<8;ni++)
          #pragma unroll
          for (int r=0;r<4;r++)
            sc[mi][ni][r] *= scale;
    }

    #pragma unroll
    for (int mi=0;mi<2;mi++){
      #pragma unroll
      for (int r=0;r<4;r++){
        float mx = sc[mi][0][r];
        #pragma unroll
        for (int ni=1;ni<8;ni++) mx = fmaxf(mx, sc[mi][ni][r]);
        mx = fmaxf(mx, __shfl_xor(mx,1,64));
        mx = fmaxf(mx, __shfl_xor(mx,2,64));
        mx = fmaxf(mx, __shfl_xor(mx,4,64));
        mx = fmaxf(mx, __shfl_xor(mx,8,64));
        float mnew = fmaxf(m_run[mi][r], mx);
        float corr = __expf(m_run[mi][r] - mnew);
        m_run[mi][r] = mnew;
        float rsum = 0.f;
        #pragma unroll
        for (int ni=0;ni<8;ni++){
          float p = __expf(sc[mi][ni][r] - mnew);
          sc[mi][ni][r] = p;
          rsum += p;
        }
        rsum += __shfl_xor(rsum,1,64);
        rsum += __shfl_xor(rsum,2,64);
        rsum += __shfl_xor(rsum,4,64);
        rsum += __shfl_xor(rsum,8,64);
        l_run[mi][r] = l_run[mi][r]*corr + rsum;
        #pragma unroll
        for (int di=0;di<4;di++) out[mi][di][r] *= corr;
      }
    }

    #pragma unroll
    for (int mi=0;mi<2;mi++)
      #pragma unroll
      for (int ni=0;ni<8;ni++)
        #pragma unroll
        for (int r=0;r<4;r++)
          Ps[wq + mi*16 + kgrp*4 + r][ni*16 + lrow] = f2b(sc[mi][ni][r]);
    __syncthreads();

    #pragma unroll
    for (int ks2=0;ks2<4;ks2++){
      bf16x8 pa[2];
      #pragma unroll
      for (int mi=0;mi<2;mi++) pa[mi] = *(const bf16x8*)&Ps[wq+mi*16+lrow][ks2*32+kgrp*8];
      #pragma unroll
      for (int di=0;di<4;di++){
        bf16x8 vf = *(const bf16x8*)&Vt[di*16+lrow][ks2*32+kgrp*8];
        out[0][di] = MFMA16(pa[0], vf, out[0][di]);
        out[1][di] = MFMA16(pa[1], vf, out[1][di]);
      }
    }
  }

  #pragma unroll
  for (int mi=0;mi<2;mi++)
    #pragma unroll
    for (int di=0;di<4;di++)
      #pragma unroll
      for (int r=0;r<4;r++){
        float o = out[mi][di][r] / l_run[mi][r];
        ctxb[(size_t)(b*1024 + qt*128 + wq + mi*16 + kgrp*4 + r)*2048
             + h*64 + di*16 + lrow] = f2b(o);
      }
}

// ---------------- Output projection (m97 structure) -------------------------
__global__ __launch_bounds__(256) void k_oproj(
    const unsigned short* __restrict__ A, const unsigned short* __restrict__ Bt,
    float* __restrict__ out)
{
  __shared__ unsigned short As[128*32];
  __shared__ unsigned short Bs[128*32];
  const int bm = blockIdx.y*128, bn = blockIdx.x*128;
  const int tid=threadIdx.x, wave=tid>>6, lane=tid&63;
  const int lrow=lane&15, kgrp=lane>>4;
  const int wm=(wave>>1)*64, wn=(wave&1)*64;
  f32x4 acc[4][4] = {};

  for (int k0=0;k0<2048;k0+=32){
    __syncthreads();
    #pragma unroll
    for (int it=0; it<2; ++it){
      int idx = it*256 + tid;
      int row = idx>>2, c16 = idx&3;
      gload16(&A [(size_t)(bm+row)*2048 + k0 + c16*8], &As[(it*256 + wave*64)*8]);
      gload16(&Bt[(size_t)(bn+row)*2048 + k0 + c16*8], &Bs[(it*256 + wave*64)*8]);
    }
    __syncthreads();
    bf16x8 a[4], b[4];
    #pragma unroll
    for (int mi=0;mi<4;mi++) a[mi] = *(const bf16x8*)&As[(wm+mi*16+lrow)*32 + kgrp*8];
    #pragma unroll
    for (int ni=0;ni<4;ni++) b[ni] = *(const bf16x8*)&Bs[(wn+ni*16+lrow)*32 + kgrp*8];
    #pragma unroll
    for (int mi=0;mi<4;mi++)
      #pragma unroll
      for (int ni=0;ni<4;ni++)
        acc[mi][ni] = MFMA16(a[mi], b[ni], acc[mi][ni]);
  }

  #pragma unroll
  for (int mi=0;mi<4;mi++)
    #pragma unroll
    for (int ni=0;ni<4;ni++){
      int gr0 = bm + wm + mi*16 + kgrp*4;
      int gc  = bn + wn + ni*16 + lrow;
      #pragma unroll
      for (int r=0;r<4;r++)
        out[(size_t)(gr0+r)*2048 + gc] = acc[mi][ni][r];
    }
}

// ---------------- launch ----------------------------------------------------
extern "C" void kernel_launch(void* const* d_in, const int* in_sizes, int n_in,
                              void* d_out, int out_size, void* d_ws, size_t ws_size,
                              hipStream_t stream)
{
  const float* X  = (const float*)d_in[0];
  const float* Wq = (const float*)d_in[1];
  const float* Wk = (const float*)d_in[2];
  const float* Wv = (const float*)d_in[3];
  const float* Wo = (const float*)d_in[4];
  float* out = (float*)d_out;
  char* ws = (char*)d_ws;

  const size_t MB = 1048576;
  float* ct = (float*)ws;                                   // 128 KB
  float* st = (float*)(ws + 128*1024);                      // 128 KB
  unsigned short* Xb   = (unsigned short*)(ws + 256*1024);            // 8 MB
  unsigned short* Wt   = (unsigned short*)(ws + 256*1024 + 8*MB);     // 12 MB
  unsigned short* Wot  = (unsigned short*)(ws + 256*1024 + 20*MB);    // 8 MB
  unsigned short* qb   = (unsigned short*)(ws + 256*1024 + 28*MB);    // 8 MB
  unsigned short* kb   = (unsigned short*)(ws + 256*1024 + 36*MB);    // 2 MB
  unsigned short* vb   = (unsigned short*)(ws + 256*1024 + 38*MB);    // 2 MB
  unsigned short* ctxb = (unsigned short*)(ws + 256*1024 + 40*MB);    // 8 MB

  hipLaunchKernelGGL(k_rope_table, dim3(128), dim3(256), 0, stream, ct, st);
  hipLaunchKernelGGL(k_cvt, dim3(2048), dim3(256), 0, stream, X, Xb, 2048*2048/4);
  hipLaunchKernelGGL(k_prep_wt, dim3(96,64), dim3(256), 0, stream, Wq, Wk, Wv, Wt);
  hipLaunchKernelGGL(k_prep_wo, dim3(64,64), dim3(256), 0, stream, Wo, Wot);
  hipLaunchKernelGGL(k_qkv, dim3(24,16), dim3(256), 0, stream,
                     Xb, Wt, ct, st, qb, kb, vb);
  hipLaunchKernelGGL(k_attn, dim3(512), dim3(256), 0, stream, qb, kb, vb, ctxb);
  hipLaunchKernelGGL(k_oproj, dim3(16,16), dim3(256), 0, stream, ctxb, Wot, out);
}

// Round 3
// 176.431 us; speedup vs baseline: 2.2062x; 1.2496x over previous
//
#include <hip/hip_runtime.h>
#include <hip/hip_bf16.h>

typedef __attribute__((ext_vector_type(8))) __bf16 bf16x8;
typedef __attribute__((ext_vector_type(4))) float f32x4;

#define MFMA16(a,b,c) __builtin_amdgcn_mfma_f32_16x16x32_bf16(a,b,c,0,0,0)

__device__ __forceinline__ unsigned short f2b(float x){
  __hip_bfloat16 h = __float2bfloat16(x);
  return __builtin_bit_cast(unsigned short, h);
}

// async global->LDS, 16B per lane. LDS dest is wave-uniform base + lane*16.
__device__ __forceinline__ void gload16(const unsigned short* g, unsigned short* l){
  __builtin_amdgcn_global_load_lds(
      (const __attribute__((address_space(1))) unsigned int*)g,
      (__attribute__((address_space(3))) unsigned int*)l, 16, 0, 0);
}

// ---------------- RoPE table: cos/sin for 1024 positions x 32 freqs ---------
__global__ void k_rope_table(float* __restrict__ ct, float* __restrict__ st){
  int i = blockIdx.x*256 + threadIdx.x;   // 0..32767
  int t = i >> 5, f = i & 31;
  float freq = powf(10000.0f, -(float)f/32.0f);
  float a = (float)t * freq;
  ct[i] = cosf(a);
  st[i] = sinf(a);
}

// ---------------- X fp32 -> bf16 (row-major) --------------------------------
__global__ void k_cvt(const float* __restrict__ src, unsigned short* __restrict__ dst, int n4){
  int i = blockIdx.x*256 + threadIdx.x;
  int stride = gridDim.x*256;
  for (; i < n4; i += stride){
    float4 v = ((const float4*)src)[i];
    ushort4 o; o.x=f2b(v.x); o.y=f2b(v.y); o.z=f2b(v.z); o.w=f2b(v.w);
    ((ushort4*)dst)[i] = o;
  }
}

// ---------------- W [K][N] fp32 -> Wt [N][K] bf16 (fused Q|K|V) -------------
__global__ __launch_bounds__(256) void k_prep_wt(
    const float* __restrict__ Wq, const float* __restrict__ Wk,
    const float* __restrict__ Wv, unsigned short* __restrict__ Wt){
  __shared__ float t[32][33];
  int n0 = blockIdx.x*32, k0 = blockIdx.y*32;
  const float* src; int N, nl;
  if (n0 < 2048)      { src=Wq; N=2048; nl=n0; }
  else if (n0 < 2560) { src=Wk; N=512;  nl=n0-2048; }
  else                { src=Wv; N=512;  nl=n0-2560; }
  int r = threadIdx.x>>5, c = threadIdx.x&31;
  #pragma unroll
  for (int it=0; it<4; ++it)
    t[r+8*it][c] = src[(size_t)(k0+r+8*it)*N + nl + c];
  __syncthreads();
  #pragma unroll
  for (int it=0; it<4; ++it)
    Wt[(size_t)(n0+r+8*it)*2048 + k0 + c] = f2b(t[c][r+8*it]);
}

__global__ __launch_bounds__(256) void k_prep_wo(
    const float* __restrict__ Wo, unsigned short* __restrict__ Wot){
  __shared__ float t[32][33];
  int n0 = blockIdx.x*32, k0 = blockIdx.y*32;
  int r = threadIdx.x>>5, c = threadIdx.x&31;
  #pragma unroll
  for (int it=0; it<4; ++it)
    t[r+8*it][c] = Wo[(size_t)(k0+r+8*it)*2048 + n0 + c];
  __syncthreads();
  #pragma unroll
  for (int it=0; it<4; ++it)
    Wot[(size_t)(n0+r+8*it)*2048 + k0 + c] = f2b(t[c][r+8*it]);
}

// ---------------- QKV GEMM (m97 structure) + RoPE epilogue ------------------
__global__ __launch_bounds__(256) void k_qkv(
    const unsigned short* __restrict__ A, const unsigned short* __restrict__ Bt,
    const float* __restrict__ ct, const float* __restrict__ st,
    unsigned short* __restrict__ qb, unsigned short* __restrict__ kb,
    unsigned short* __restrict__ vb)
{
  __shared__ unsigned short As[128*32];
  __shared__ unsigned short Bs[128*32];
  const int bm = blockIdx.y*128, bn_g = blockIdx.x*128;
  const int tid=threadIdx.x, wave=tid>>6, lane=tid&63;
  const int lrow=lane&15, kgrp=lane>>4;
  const int wm=(wave>>1)*64, wn=(wave&1)*64;
  f32x4 acc[4][4] = {};

  for (int k0=0;k0<2048;k0+=32){
    __syncthreads();
    #pragma unroll
    for (int it=0; it<2; ++it){
      int idx = it*256 + tid;
      int row = idx>>2, c16 = idx&3;
      gload16(&A [(size_t)(bm  +row)*2048 + k0 + c16*8], &As[(it*256 + wave*64)*8]);
      gload16(&Bt[(size_t)(bn_g+row)*2048 + k0 + c16*8], &Bs[(it*256 + wave*64)*8]);
    }
    __syncthreads();
    bf16x8 a[4], b[4];
    #pragma unroll
    for (int mi=0;mi<4;mi++) a[mi] = *(const bf16x8*)&As[(wm+mi*16+lrow)*32 + kgrp*8];
    #pragma unroll
    for (int ni=0;ni<4;ni++) b[ni] = *(const bf16x8*)&Bs[(wn+ni*16+lrow)*32 + kgrp*8];
    #pragma unroll
    for (int mi=0;mi<4;mi++)
      #pragma unroll
      for (int ni=0;ni<4;ni++)
        acc[mi][ni] = MFMA16(a[mi], b[ni], acc[mi][ni]);
  }

  const int wtype = (bn_g < 2048) ? 0 : (bn_g < 2560 ? 1 : 2);
  #pragma unroll
  for (int mi=0;mi<4;mi++){
    #pragma unroll
    for (int ni=0;ni<4;ni++){
      int gr0 = bm + wm + mi*16 + kgrp*4;
      int gc  = bn_g + wn + ni*16 + lrow;
      if (wtype==2){
        int c = gc - 2560;
        #pragma unroll
        for (int r=0;r<4;r++)
          vb[(size_t)(gr0+r)*512 + c] = f2b(acc[mi][ni][r]);
      } else {
        int d = gc & 63, fi = d >> 1, odd = d & 1;
        #pragma unroll
        for (int r=0;r<4;r++){
          float x = acc[mi][ni][r];
          float p = __shfl_xor(x, 1, 64);
          int srow = (gr0 + r) & 1023;
          float c = ct[srow*32 + fi], sn = st[srow*32 + fi];
          float o = odd ? (x*c + p*sn) : (x*c - p*sn);
          if (wtype==0) qb[(size_t)(gr0+r)*2048 + gc] = f2b(o);
          else          kb[(size_t)(gr0+r)*512 + (gc-2048)] = f2b(o);
        }
      }
    }
  }
}

// ---------------- Flash attention (GQA, causal) -----------------------------
// grid 512: p = bid>>6 (0..7) -> this block does q-tiles {15-p, p} (64 rows
// each) => every block runs exactly 17 KV iterations (perfect balance).
// 4 waves x 16 q-rows. LDS 27.7KB -> multi-block residency.
#define LDP 74   // padded row length (ushorts): dword stride 37 -> conflict-free b128 reads
__global__ __launch_bounds__(256) void k_attn(
    const unsigned short* __restrict__ qb, const unsigned short* __restrict__ kb,
    const unsigned short* __restrict__ vb, unsigned short* __restrict__ ctxb)
{
  __shared__ unsigned short Ks[64*LDP];
  __shared__ unsigned short Vt[64*LDP];
  __shared__ unsigned short QP[64*LDP];   // Q tile, then reused for P (wave-private rows)

  const int p  = blockIdx.x >> 6;
  const int bh = blockIdx.x & 63;
  const int h  = bh & 31;
  const int b  = bh >> 5;
  const int kvh = h >> 2;

  const int tid=threadIdx.x, wave=tid>>6, lane=tid&63;
  const int lrow=lane&15, kgrp=lane>>4;
  const int wq = wave*16;
  const int sr = tid>>2, seg = (tid&3)*16;   // staging map: row, d-segment

  #pragma unroll
  for (int phase=0; phase<2; ++phase){
    const int qt = phase==0 ? 15-p : p;
    const int q0 = qt*64;

    __syncthreads();   // all waves done reading QP (prev phase P)
    { // stage Q tile 64x64
      const unsigned short* src = qb + (size_t)(b*1024 + q0 + sr)*2048 + h*64 + seg;
      *(uint4*)&QP[sr*LDP + seg]     = *(const uint4*)&src[0];
      *(uint4*)&QP[sr*LDP + seg + 8] = *(const uint4*)&src[8];
    }
    __syncthreads();

    bf16x8 qa[2];
    #pragma unroll
    for (int ks=0;ks<2;ks++)
      qa[ks] = *(const bf16x8*)&QP[(wq+lrow)*LDP + ks*32 + kgrp*8];

    float m_run[4], l_run[4];
    f32x4 out[4] = {};
    #pragma unroll
    for (int r=0;r<4;r++){ m_run[r] = -1e30f; l_run[r] = 0.f; }

    for (int j=0;j<=qt;j++){
      __syncthreads();   // Ks/Vt free (all waves past last tile's MFMA reads)
      { // stage K (row-major) + V (transposed)
        const unsigned short* ksrc = kb + (size_t)(b*1024 + j*64 + sr)*512 + kvh*64 + seg;
        *(uint4*)&Ks[sr*LDP + seg]     = *(const uint4*)&ksrc[0];
        *(uint4*)&Ks[sr*LDP + seg + 8] = *(const uint4*)&ksrc[8];
        const unsigned short* vsrc = vb + (size_t)(b*1024 + j*64 + sr)*512 + kvh*64 + seg;
        uint4 v0 = *(const uint4*)&vsrc[0];
        uint4 v1 = *(const uint4*)&vsrc[8];
        const unsigned short* e0 = (const unsigned short*)&v0;
        const unsigned short* e1 = (const unsigned short*)&v1;
        #pragma unroll
        for (int e=0;e<8;e++){
          Vt[(seg+e)*LDP + sr]   = e0[e];
          Vt[(seg+8+e)*LDP + sr] = e1[e];
        }
      }
      __syncthreads();

      // S = Q K^T : 16q x 64kv per wave
      f32x4 sc[4] = {};
      #pragma unroll
      for (int ks=0;ks<2;ks++){
        #pragma unroll
        for (int ni=0;ni<4;ni++){
          bf16x8 kf = *(const bf16x8*)&Ks[(ni*16+lrow)*LDP + ks*32 + kgrp*8];
          sc[ni] = MFMA16(qa[ks], kf, sc[ni]);
        }
      }

      const float scale = 0.125f;
      if (j == qt){
        #pragma unroll
        for (int ni=0;ni<4;ni++)
          #pragma unroll
          for (int r=0;r<4;r++){
            int qrl = wq + kgrp*4 + r;
            int kcl = ni*16 + lrow;
            float sv = sc[ni][r]*scale;
            sc[ni][r] = (kcl > qrl) ? -1e30f : sv;
          }
      } else {
        #pragma unroll
        for (int ni=0;ni<4;ni++)
          #pragma unroll
          for (int r=0;r<4;r++)
            sc[ni][r] *= scale;
      }

      // online softmax (row stats replicated across 16-lane col groups)
      #pragma unroll
      for (int r=0;r<4;r++){
        float mx = fmaxf(fmaxf(sc[0][r], sc[1][r]), fmaxf(sc[2][r], sc[3][r]));
        mx = fmaxf(mx, __shfl_xor(mx,1,64));
        mx = fmaxf(mx, __shfl_xor(mx,2,64));
        mx = fmaxf(mx, __shfl_xor(mx,4,64));
        mx = fmaxf(mx, __shfl_xor(mx,8,64));
        float mnew = fmaxf(m_run[r], mx);
        float corr = __expf(m_run[r] - mnew);
        m_run[r] = mnew;
        float rsum = 0.f;
        #pragma unroll
        for (int ni=0;ni<4;ni++){
          float pv = __expf(sc[ni][r] - mnew);
          sc[ni][r] = pv;
          rsum += pv;
        }
        rsum += __shfl_xor(rsum,1,64);
        rsum += __shfl_xor(rsum,2,64);
        rsum += __shfl_xor(rsum,4,64);
        rsum += __shfl_xor(rsum,8,64);
        l_run[r] = l_run[r]*corr + rsum;
        #pragma unroll
        for (int di=0;di<4;di++) out[di][r] *= corr;
      }

      // P -> LDS (wave-private rows; no barrier needed)
      #pragma unroll
      for (int ni=0;ni<4;ni++)
        #pragma unroll
        for (int r=0;r<4;r++)
          QP[(wq + kgrp*4 + r)*LDP + ni*16 + lrow] = f2b(sc[ni][r]);

      // O += P V
      #pragma unroll
      for (int ks2=0;ks2<2;ks2++){
        bf16x8 pa = *(const bf16x8*)&QP[(wq+lrow)*LDP + ks2*32 + kgrp*8];
        #pragma unroll
        for (int di=0;di<4;di++){
          bf16x8 vf = *(const bf16x8*)&Vt[(di*16+lrow)*LDP + ks2*32 + kgrp*8];
          out[di] = MFMA16(pa, vf, out[di]);
        }
      }
    }

    #pragma unroll
    for (int di=0;di<4;di++)
      #pragma unroll
      for (int r=0;r<4;r++){
        float o = out[di][r] / l_run[r];
        ctxb[(size_t)(b*1024 + q0 + wq + kgrp*4 + r)*2048
             + h*64 + di*16 + lrow] = f2b(o);
      }
  }
}

// ---------------- Output projection (m97 structure) -------------------------
__global__ __launch_bounds__(256) void k_oproj(
    const unsigned short* __restrict__ A, const unsigned short* __restrict__ Bt,
    float* __restrict__ out)
{
  __shared__ unsigned short As[128*32];
  __shared__ unsigned short Bs[128*32];
  const int bm = blockIdx.y*128, bn = blockIdx.x*128;
  const int tid=threadIdx.x, wave=tid>>6, lane=tid&63;
  const int lrow=lane&15, kgrp=lane>>4;
  const int wm=(wave>>1)*64, wn=(wave&1)*64;
  f32x4 acc[4][4] = {};

  for (int k0=0;k0<2048;k0+=32){
    __syncthreads();
    #pragma unroll
    for (int it=0; it<2; ++it){
      int idx = it*256 + tid;
      int row = idx>>2, c16 = idx&3;
      gload16(&A [(size_t)(bm+row)*2048 + k0 + c16*8], &As[(it*256 + wave*64)*8]);
      gload16(&Bt[(size_t)(bn+row)*2048 + k0 + c16*8], &Bs[(it*256 + wave*64)*8]);
    }
    __syncthreads();
    bf16x8 a[4], b[4];
    #pragma unroll
    for (int mi=0;mi<4;mi++) a[mi] = *(const bf16x8*)&As[(wm+mi*16+lrow)*32 + kgrp*8];
    #pragma unroll
    for (int ni=0;ni<4;ni++) b[ni] = *(const bf16x8*)&Bs[(wn+ni*16+lrow)*32 + kgrp*8];
    #pragma unroll
    for (int mi=0;mi<4;mi++)
      #pragma unroll
      for (int ni=0;ni<4;ni++)
        acc[mi][ni] = MFMA16(a[mi], b[ni], acc[mi][ni]);
  }

  #pragma unroll
  for (int mi=0;mi<4;mi++)
    #pragma unroll
    for (int ni=0;ni<4;ni++){
      int gr0 = bm + wm + mi*16 + kgrp*4;
      int gc  = bn + wn + ni*16 + lrow;
      #pragma unroll
      for (int r=0;r<4;r++)
        out[(size_t)(gr0+r)*2048 + gc] = acc[mi][ni][r];
    }
}

// ---------------- launch ----------------------------------------------------
extern "C" void kernel_launch(void* const* d_in, const int* in_sizes, int n_in,
                              void* d_out, int out_size, void* d_ws, size_t ws_size,
                              hipStream_t stream)
{
  const float* X  = (const float*)d_in[0];
  const float* Wq = (const float*)d_in[1];
  const float* Wk = (const float*)d_in[2];
  const float* Wv = (const float*)d_in[3];
  const float* Wo = (const float*)d_in[4];
  float* out = (float*)d_out;
  char* ws = (char*)d_ws;

  const size_t MB = 1048576;
  float* ct = (float*)ws;                                   // 128 KB
  float* st = (float*)(ws + 128*1024);                      // 128 KB
  unsigned short* Xb   = (unsigned short*)(ws + 256*1024);            // 8 MB
  unsigned short* Wt   = (unsigned short*)(ws + 256*1024 + 8*MB);     // 12 MB
  unsigned short* Wot  = (unsigned short*)(ws + 256*1024 + 20*MB);    // 8 MB
  unsigned short* qb   = (unsigned short*)(ws + 256*1024 + 28*MB);    // 8 MB
  unsigned short* kb   = (unsigned short*)(ws + 256*1024 + 36*MB);    // 2 MB
  unsigned short* vb   = (unsigned short*)(ws + 256*1024 + 38*MB);    // 2 MB
  unsigned short* ctxb = (unsigned short*)(ws + 256*1024 + 40*MB);    // 8 MB

  hipLaunchKernelGGL(k_rope_table, dim3(128), dim3(256), 0, stream, ct, st);
  hipLaunchKernelGGL(k_cvt, dim3(2048), dim3(256), 0, stream, X, Xb, 2048*2048/4);
  hipLaunchKernelGGL(k_prep_wt, dim3(96,64), dim3(256), 0, stream, Wq, Wk, Wv, Wt);
  hipLaunchKernelGGL(k_prep_wo, dim3(64,64), dim3(256), 0, stream, Wo, Wot);
  hipLaunchKernelGGL(k_qkv, dim3(24,16), dim3(256), 0, stream,
                     Xb, Wt, ct, st, qb, kb, vb);
  hipLaunchKernelGGL(k_attn, dim3(512), dim3(256), 0, stream, qb, kb, vb, ctxb);
  hipLaunchKernelGGL(k_oproj, dim3(16,16), dim3(256), 0, stream, ctxb, Wot, out);
}

// Round 4
// 163.082 us; speedup vs baseline: 2.3867x; 1.0819x over previous
//
#include <hip/hip_runtime.h>
#include <hip/hip_bf16.h>

typedef __attribute__((ext_vector_type(8))) __bf16 bf16x8;
typedef __attribute__((ext_vector_type(4))) float f32x4;

#define MFMA16(a,b,c) __builtin_amdgcn_mfma_f32_16x16x32_bf16(a,b,c,0,0,0)

__device__ __forceinline__ unsigned short f2b(float x){
  __hip_bfloat16 h = __float2bfloat16(x);
  return __builtin_bit_cast(unsigned short, h);
}

// async global->LDS, 16B per lane. LDS dest is wave-uniform base + lane*16.
__device__ __forceinline__ void gload16(const unsigned short* g, unsigned short* l){
  __builtin_amdgcn_global_load_lds(
      (const __attribute__((address_space(1))) unsigned int*)g,
      (__attribute__((address_space(3))) unsigned int*)l, 16, 0, 0);
}

// ---------------- RoPE table: cos/sin for 1024 positions x 32 freqs ---------
__global__ void k_rope_table(float* __restrict__ ct, float* __restrict__ st){
  int i = blockIdx.x*256 + threadIdx.x;   // 0..32767
  int t = i >> 5, f = i & 31;
  float freq = powf(10000.0f, -(float)f/32.0f);
  float a = (float)t * freq;
  ct[i] = cosf(a);
  st[i] = sinf(a);
}

// ---------------- X fp32 -> bf16 (row-major) --------------------------------
__global__ void k_cvt(const float* __restrict__ src, unsigned short* __restrict__ dst, int n4){
  int i = blockIdx.x*256 + threadIdx.x;
  int stride = gridDim.x*256;
  for (; i < n4; i += stride){
    float4 v = ((const float4*)src)[i];
    ushort4 o; o.x=f2b(v.x); o.y=f2b(v.y); o.z=f2b(v.z); o.w=f2b(v.w);
    ((ushort4*)dst)[i] = o;
  }
}

// ---------------- W [K][N] fp32 -> Wt [N][K] bf16 (fused Q|K|V) -------------
__global__ __launch_bounds__(256) void k_prep_wt(
    const float* __restrict__ Wq, const float* __restrict__ Wk,
    const float* __restrict__ Wv, unsigned short* __restrict__ Wt){
  __shared__ float t[32][33];
  int n0 = blockIdx.x*32, k0 = blockIdx.y*32;
  const float* src; int N, nl;
  if (n0 < 2048)      { src=Wq; N=2048; nl=n0; }
  else if (n0 < 2560) { src=Wk; N=512;  nl=n0-2048; }
  else                { src=Wv; N=512;  nl=n0-2560; }
  int r = threadIdx.x>>5, c = threadIdx.x&31;
  #pragma unroll
  for (int it=0; it<4; ++it)
    t[r+8*it][c] = src[(size_t)(k0+r+8*it)*N + nl + c];
  __syncthreads();
  #pragma unroll
  for (int it=0; it<4; ++it)
    Wt[(size_t)(n0+r+8*it)*2048 + k0 + c] = f2b(t[c][r+8*it]);
}

__global__ __launch_bounds__(256) void k_prep_wo(
    const float* __restrict__ Wo, unsigned short* __restrict__ Wot){
  __shared__ float t[32][33];
  int n0 = blockIdx.x*32, k0 = blockIdx.y*32;
  int r = threadIdx.x>>5, c = threadIdx.x&31;
  #pragma unroll
  for (int it=0; it<4; ++it)
    t[r+8*it][c] = Wo[(size_t)(k0+r+8*it)*2048 + n0 + c];
  __syncthreads();
  #pragma unroll
  for (int it=0; it<4; ++it)
    Wot[(size_t)(n0+r+8*it)*2048 + k0 + c] = f2b(t[c][r+8*it]);
}

// ---------------- QKV GEMM: 128x64 tile, BK=32, double-buffered -------------
// grid 768 (16 m-tiles x 48 n-tiles) = 3 blocks/CU, perfectly balanced.
__global__ __launch_bounds__(256) void k_qkv(
    const unsigned short* __restrict__ A, const unsigned short* __restrict__ Bt,
    const float* __restrict__ ct, const float* __restrict__ st,
    unsigned short* __restrict__ qb, unsigned short* __restrict__ kb,
    unsigned short* __restrict__ vb)
{
  __shared__ unsigned short As[2][128*32];
  __shared__ unsigned short Bs[2][64*32];
  const int mt = blockIdx.x & 15;
  const int nt = blockIdx.x >> 4;         // 0..47
  const int bm = mt*128, bn_g = nt*64;
  const int tid=threadIdx.x, wave=tid>>6, lane=tid&63;
  const int lrow=lane&15, kgrp=lane>>4;
  const int wm=(wave>>1)*64, wn=(wave&1)*32;
  const int arow = tid>>2, ac16 = (tid&3)*8;
  f32x4 acc[4][2] = {};

  #define STAGE_Q(buf, k0) do {                                                              \
    gload16(&A [(size_t)(bm + arow     )*2048 + (k0) + ac16], &As[buf][(wave*64)*8]);        \
    gload16(&A [(size_t)(bm + 64 + arow)*2048 + (k0) + ac16], &As[buf][(256 + wave*64)*8]);  \
    gload16(&Bt[(size_t)(bn_g + arow   )*2048 + (k0) + ac16], &Bs[buf][(wave*64)*8]);        \
  } while(0)

  #define COMPUTE_Q(buf) do {                                          \
    bf16x8 a0,a1,a2,a3,b0,b1;                                          \
    a0 = *(const bf16x8*)&As[buf][(wm+ 0+lrow)*32 + kgrp*8];           \
    a1 = *(const bf16x8*)&As[buf][(wm+16+lrow)*32 + kgrp*8];           \
    a2 = *(const bf16x8*)&As[buf][(wm+32+lrow)*32 + kgrp*8];           \
    a3 = *(const bf16x8*)&As[buf][(wm+48+lrow)*32 + kgrp*8];           \
    b0 = *(const bf16x8*)&Bs[buf][(wn+ 0+lrow)*32 + kgrp*8];           \
    b1 = *(const bf16x8*)&Bs[buf][(wn+16+lrow)*32 + kgrp*8];           \
    acc[0][0]=MFMA16(a0,b0,acc[0][0]); acc[0][1]=MFMA16(a0,b1,acc[0][1]); \
    acc[1][0]=MFMA16(a1,b0,acc[1][0]); acc[1][1]=MFMA16(a1,b1,acc[1][1]); \
    acc[2][0]=MFMA16(a2,b0,acc[2][0]); acc[2][1]=MFMA16(a2,b1,acc[2][1]); \
    acc[3][0]=MFMA16(a3,b0,acc[3][0]); acc[3][1]=MFMA16(a3,b1,acc[3][1]); \
  } while(0)

  STAGE_Q(0, 0);
  asm volatile("s_waitcnt vmcnt(0)" ::: "memory");
  __syncthreads();
  #pragma unroll 1
  for (int t=0; t<63; ++t){
    const int cur = t&1;
    STAGE_Q(cur^1, (t+1)*32);     // issue next tile's loads (latency hides under compute)
    COMPUTE_Q(cur);
    asm volatile("s_waitcnt vmcnt(0)" ::: "memory");
    __syncthreads();
  }
  COMPUTE_Q(1);

  const int wtype = (bn_g < 2048) ? 0 : (bn_g < 2560 ? 1 : 2);
  #pragma unroll
  for (int mi=0;mi<4;mi++){
    #pragma unroll
    for (int ni=0;ni<2;ni++){
      int gr0 = bm + wm + mi*16 + kgrp*4;
      int gc  = bn_g + wn + ni*16 + lrow;
      if (wtype==2){
        int c = gc - 2560;
        #pragma unroll
        for (int r=0;r<4;r++)
          vb[(size_t)(gr0+r)*512 + c] = f2b(acc[mi][ni][r]);
      } else {
        int d = gc & 63, fi = d >> 1, odd = d & 1;
        #pragma unroll
        for (int r=0;r<4;r++){
          float x = acc[mi][ni][r];
          float p = __shfl_xor(x, 1, 64);
          int srow = (gr0 + r) & 1023;
          float c = ct[srow*32 + fi], sn = st[srow*32 + fi];
          float o = odd ? (x*c + p*sn) : (x*c - p*sn);
          if (wtype==0) qb[(size_t)(gr0+r)*2048 + gc] = f2b(o);
          else          kb[(size_t)(gr0+r)*512 + (gc-2048)] = f2b(o);
        }
      }
    }
  }
  #undef STAGE_Q
  #undef COMPUTE_Q
}

// ---------------- Flash attention (GQA, causal) -----------------------------
// grid 512: p = bid>>6 -> q-tiles {15-p, p}: every block = exactly 17 KV iters.
#define LDP 74
__global__ __launch_bounds__(256) void k_attn(
    const unsigned short* __restrict__ qb, const unsigned short* __restrict__ kb,
    const unsigned short* __restrict__ vb, unsigned short* __restrict__ ctxb)
{
  __shared__ unsigned short Ks[64*LDP];
  __shared__ unsigned short Vt[64*LDP];
  __shared__ unsigned short QP[64*LDP];

  const int p  = blockIdx.x >> 6;
  const int bh = blockIdx.x & 63;
  const int h  = bh & 31;
  const int b  = bh >> 5;
  const int kvh = h >> 2;

  const int tid=threadIdx.x, wave=tid>>6, lane=tid&63;
  const int lrow=lane&15, kgrp=lane>>4;
  const int wq = wave*16;
  const int sr = tid>>2, seg = (tid&3)*16;

  #pragma unroll
  for (int phase=0; phase<2; ++phase){
    const int qt = phase==0 ? 15-p : p;
    const int q0 = qt*64;

    __syncthreads();
    {
      const unsigned short* src = qb + (size_t)(b*1024 + q0 + sr)*2048 + h*64 + seg;
      *(uint4*)&QP[sr*LDP + seg]     = *(const uint4*)&src[0];
      *(uint4*)&QP[sr*LDP + seg + 8] = *(const uint4*)&src[8];
    }
    __syncthreads();

    bf16x8 qa[2];
    #pragma unroll
    for (int ks=0;ks<2;ks++)
      qa[ks] = *(const bf16x8*)&QP[(wq+lrow)*LDP + ks*32 + kgrp*8];

    float m_run[4], l_run[4];
    f32x4 out[4] = {};
    #pragma unroll
    for (int r=0;r<4;r++){ m_run[r] = -1e30f; l_run[r] = 0.f; }

    for (int j=0;j<=qt;j++){
      __syncthreads();
      {
        const unsigned short* ksrc = kb + (size_t)(b*1024 + j*64 + sr)*512 + kvh*64 + seg;
        *(uint4*)&Ks[sr*LDP + seg]     = *(const uint4*)&ksrc[0];
        *(uint4*)&Ks[sr*LDP + seg + 8] = *(const uint4*)&ksrc[8];
        const unsigned short* vsrc = vb + (size_t)(b*1024 + j*64 + sr)*512 + kvh*64 + seg;
        uint4 v0 = *(const uint4*)&vsrc[0];
        uint4 v1 = *(const uint4*)&vsrc[8];
        const unsigned short* e0 = (const unsigned short*)&v0;
        const unsigned short* e1 = (const unsigned short*)&v1;
        #pragma unroll
        for (int e=0;e<8;e++){
          Vt[(seg+e)*LDP + sr]   = e0[e];
          Vt[(seg+8+e)*LDP + sr] = e1[e];
        }
      }
      __syncthreads();

      f32x4 sc[4] = {};
      #pragma unroll
      for (int ks=0;ks<2;ks++){
        #pragma unroll
        for (int ni=0;ni<4;ni++){
          bf16x8 kf = *(const bf16x8*)&Ks[(ni*16+lrow)*LDP + ks*32 + kgrp*8];
          sc[ni] = MFMA16(qa[ks], kf, sc[ni]);
        }
      }

      const float scale = 0.125f;
      if (j == qt){
        #pragma unroll
        for (int ni=0;ni<4;ni++)
          #pragma unroll
          for (int r=0;r<4;r++){
            int qrl = wq + kgrp*4 + r;
            int kcl = ni*16 + lrow;
            float sv = sc[ni][r]*scale;
            sc[ni][r] = (kcl > qrl) ? -1e30f : sv;
          }
      } else {
        #pragma unroll
        for (int ni=0;ni<4;ni++)
          #pragma unroll
          for (int r=0;r<4;r++)
            sc[ni][r] *= scale;
      }

      #pragma unroll
      for (int r=0;r<4;r++){
        float mx = fmaxf(fmaxf(sc[0][r], sc[1][r]), fmaxf(sc[2][r], sc[3][r]));
        mx = fmaxf(mx, __shfl_xor(mx,1,64));
        mx = fmaxf(mx, __shfl_xor(mx,2,64));
        mx = fmaxf(mx, __shfl_xor(mx,4,64));
        mx = fmaxf(mx, __shfl_xor(mx,8,64));
        float mnew = fmaxf(m_run[r], mx);
        float corr = __expf(m_run[r] - mnew);
        m_run[r] = mnew;
        float rsum = 0.f;
        #pragma unroll
        for (int ni=0;ni<4;ni++){
          float pv = __expf(sc[ni][r] - mnew);
          sc[ni][r] = pv;
          rsum += pv;
        }
        rsum += __shfl_xor(rsum,1,64);
        rsum += __shfl_xor(rsum,2,64);
        rsum += __shfl_xor(rsum,4,64);
        rsum += __shfl_xor(rsum,8,64);
        l_run[r] = l_run[r]*corr + rsum;
        #pragma unroll
        for (int di=0;di<4;di++) out[di][r] *= corr;
      }

      #pragma unroll
      for (int ni=0;ni<4;ni++)
        #pragma unroll
        for (int r=0;r<4;r++)
          QP[(wq + kgrp*4 + r)*LDP + ni*16 + lrow] = f2b(sc[ni][r]);

      #pragma unroll
      for (int ks2=0;ks2<2;ks2++){
        bf16x8 pa = *(const bf16x8*)&QP[(wq+lrow)*LDP + ks2*32 + kgrp*8];
        #pragma unroll
        for (int di=0;di<4;di++){
          bf16x8 vf = *(const bf16x8*)&Vt[(di*16+lrow)*LDP + ks2*32 + kgrp*8];
          out[di] = MFMA16(pa, vf, out[di]);
        }
      }
    }

    #pragma unroll
    for (int di=0;di<4;di++)
      #pragma unroll
      for (int r=0;r<4;r++){
        float o = out[di][r] / l_run[r];
        ctxb[(size_t)(b*1024 + q0 + wq + kgrp*4 + r)*2048
             + h*64 + di*16 + lrow] = f2b(o);
      }
  }
}

// ---------------- Output projection: 128x64 tile, double-buffered -----------
// grid 512 (16 m-tiles x 32 n-tiles) = 2 blocks/CU, balanced.
__global__ __launch_bounds__(256) void k_oproj(
    const unsigned short* __restrict__ A, const unsigned short* __restrict__ Bt,
    float* __restrict__ out)
{
  __shared__ unsigned short As[2][128*32];
  __shared__ unsigned short Bs[2][64*32];
  const int mt = blockIdx.x & 15;
  const int nt = blockIdx.x >> 4;         // 0..31
  const int bm = mt*128, bn = nt*64;
  const int tid=threadIdx.x, wave=tid>>6, lane=tid&63;
  const int lrow=lane&15, kgrp=lane>>4;
  const int wm=(wave>>1)*64, wn=(wave&1)*32;
  const int arow = tid>>2, ac16 = (tid&3)*8;
  f32x4 acc[4][2] = {};

  #define STAGE_O(buf, k0) do {                                                              \
    gload16(&A [(size_t)(bm + arow     )*2048 + (k0) + ac16], &As[buf][(wave*64)*8]);        \
    gload16(&A [(size_t)(bm + 64 + arow)*2048 + (k0) + ac16], &As[buf][(256 + wave*64)*8]);  \
    gload16(&Bt[(size_t)(bn + arow     )*2048 + (k0) + ac16], &Bs[buf][(wave*64)*8]);        \
  } while(0)

  #define COMPUTE_O(buf) do {                                          \
    bf16x8 a0,a1,a2,a3,b0,b1;                                          \
    a0 = *(const bf16x8*)&As[buf][(wm+ 0+lrow)*32 + kgrp*8];           \
    a1 = *(const bf16x8*)&As[buf][(wm+16+lrow)*32 + kgrp*8];           \
    a2 = *(const bf16x8*)&As[buf][(wm+32+lrow)*32 + kgrp*8];           \
    a3 = *(const bf16x8*)&As[buf][(wm+48+lrow)*32 + kgrp*8];           \
    b0 = *(const bf16x8*)&Bs[buf][(wn+ 0+lrow)*32 + kgrp*8];           \
    b1 = *(const bf16x8*)&Bs[buf][(wn+16+lrow)*32 + kgrp*8];           \
    acc[0][0]=MFMA16(a0,b0,acc[0][0]); acc[0][1]=MFMA16(a0,b1,acc[0][1]); \
    acc[1][0]=MFMA16(a1,b0,acc[1][0]); acc[1][1]=MFMA16(a1,b1,acc[1][1]); \
    acc[2][0]=MFMA16(a2,b0,acc[2][0]); acc[2][1]=MFMA16(a2,b1,acc[2][1]); \
    acc[3][0]=MFMA16(a3,b0,acc[3][0]); acc[3][1]=MFMA16(a3,b1,acc[3][1]); \
  } while(0)

  STAGE_O(0, 0);
  asm volatile("s_waitcnt vmcnt(0)" ::: "memory");
  __syncthreads();
  #pragma unroll 1
  for (int t=0; t<63; ++t){
    const int cur = t&1;
    STAGE_O(cur^1, (t+1)*32);
    COMPUTE_O(cur);
    asm volatile("s_waitcnt vmcnt(0)" ::: "memory");
    __syncthreads();
  }
  COMPUTE_O(1);

  #pragma unroll
  for (int mi=0;mi<4;mi++)
    #pragma unroll
    for (int ni=0;ni<2;ni++){
      int gr0 = bm + wm + mi*16 + kgrp*4;
      int gc  = bn + wn + ni*16 + lrow;
      #pragma unroll
      for (int r=0;r<4;r++)
        out[(size_t)(gr0+r)*2048 + gc] = acc[mi][ni][r];
    }
  #undef STAGE_O
  #undef COMPUTE_O
}

// ---------------- launch ----------------------------------------------------
extern "C" void kernel_launch(void* const* d_in, const int* in_sizes, int n_in,
                              void* d_out, int out_size, void* d_ws, size_t ws_size,
                              hipStream_t stream)
{
  const float* X  = (const float*)d_in[0];
  const float* Wq = (const float*)d_in[1];
  const float* Wk = (const float*)d_in[2];
  const float* Wv = (const float*)d_in[3];
  const float* Wo = (const float*)d_in[4];
  float* out = (float*)d_out;
  char* ws = (char*)d_ws;

  const size_t MB = 1048576;
  float* ct = (float*)ws;                                   // 128 KB
  float* st = (float*)(ws + 128*1024);                      // 128 KB
  unsigned short* Xb   = (unsigned short*)(ws + 256*1024);            // 8 MB
  unsigned short* Wt   = (unsigned short*)(ws + 256*1024 + 8*MB);     // 12 MB
  unsigned short* Wot  = (unsigned short*)(ws + 256*1024 + 20*MB);    // 8 MB
  unsigned short* qb   = (unsigned short*)(ws + 256*1024 + 28*MB);    // 8 MB
  unsigned short* kb   = (unsigned short*)(ws + 256*1024 + 36*MB);    // 2 MB
  unsigned short* vb   = (unsigned short*)(ws + 256*1024 + 38*MB);    // 2 MB
  unsigned short* ctxb = (unsigned short*)(ws + 256*1024 + 40*MB);    // 8 MB

  hipLaunchKernelGGL(k_rope_table, dim3(128), dim3(256), 0, stream, ct, st);
  hipLaunchKernelGGL(k_cvt, dim3(2048), dim3(256), 0, stream, X, Xb, 2048*2048/4);
  hipLaunchKernelGGL(k_prep_wt, dim3(96,64), dim3(256), 0, stream, Wq, Wk, Wv, Wt);
  hipLaunchKernelGGL(k_prep_wo, dim3(64,64), dim3(256), 0, stream, Wo, Wot);
  hipLaunchKernelGGL(k_qkv, dim3(768), dim3(256), 0, stream,
                     Xb, Wt, ct, st, qb, kb, vb);
  hipLaunchKernelGGL(k_attn, dim3(512), dim3(256), 0, stream, qb, kb, vb, ctxb);
  hipLaunchKernelGGL(k_oproj, dim3(512), dim3(256), 0, stream, ctxb, Wot, out);
}